// Round 4
// baseline (387.035 us; speedup 1.0000x reference)
//
#include <hip/hip_runtime.h>
#include <math.h>

// Problem: B=16, LQ=1024, LK=1024, DK=256, DV=256, fp32 in/out, mask int32.
// Identity: softmax_k(q_s + k_s, mask) == mask-weighted softmax of k_s alone
// (q_s constant over k cancels; masked entries exactly -1e9 -> weight 0).
// query is never read. k_s ~ N(0,16^2): keep candidates e >= 1e-11*e_max
// (C ~ 30-90 per batch, E[C]~50), track exact excluded mass; per row verify
// excl <= 1e-4*Z else exact dense fallback (P ~ 2^-35 per row).
//
// R3 lesson: NO dependent-address serial walks. Fixed trip count, linear LDS
// addresses, candidate-mask bits in wave-uniform SGPRs (ballot), 4 rows/wave
// so each V read is amortized 4x.

#define NB     16
#define NL     1024
#define ND     256
#define CMAX   128      // candidate capacity (E[C]~50, sd~7; overflow -> excl)
#define NSTAGE 56       // candidate V rows staged in LDS (56 KB)
#define THRESH 1e-11f
#define RELCHK 1e-4f

// ---------------- Kernel A: ks[b,k] = dot(key[b,k,:], w) -----------------
__global__ __launch_bounds__(256)
void ks_kernel(const float* __restrict__ key, const float* __restrict__ w,
               float* __restrict__ ks) {
    int wid  = threadIdx.x >> 6;
    int lane = threadIdx.x & 63;
    int row  = blockIdx.x * 4 + wid;               // 0 .. NB*NL-1
    const float4* krow = (const float4*)(key + (size_t)row * ND);
    float4 kv = krow[lane];
    float4 wv = ((const float4*)w)[lane];
    float p = kv.x * wv.x + kv.y * wv.y + kv.z * wv.z + kv.w * wv.w;
    #pragma unroll
    for (int off = 32; off > 0; off >>= 1)
        p += __shfl_xor(p, off, 64);
    if (lane == 0) ks[row] = p;
}

// ---- Kernel B: per batch: max, e=exp(ks-m), threshold compaction --------
// Candidate arrays are zero-padded to CMAX (pad: k=0,e=0 contributes 0).
__global__ __launch_bounds__(1024)
void compact_kernel(const float* __restrict__ ks, float* __restrict__ e_full,
                    int* __restrict__ cand_k, float* __restrict__ cand_e,
                    int* __restrict__ Carr, float* __restrict__ exclArr) {
    __shared__ float red[NL];
    __shared__ int cnt;
    const int b = blockIdx.x;
    const int t = threadIdx.x;

    float v = ks[b * NL + t];
    red[t] = v;
    if (t < CMAX) { cand_k[b * CMAX + t] = 0; cand_e[b * CMAX + t] = 0.0f; }
    if (t == 0) cnt = 0;
    __syncthreads();
    for (int off = 512; off > 0; off >>= 1) {
        if (t < off) red[t] = fmaxf(red[t], red[t + off]);
        __syncthreads();
    }
    float m = red[0];
    __syncthreads();

    float e = __expf(v - m);            // e in (0,1]
    e_full[b * NL + t] = e;
    bool kept = false;
    if (e >= THRESH) {
        int pos = atomicAdd(&cnt, 1);   // order irrelevant: any-order summation
        if (pos < CMAX) {
            cand_k[b * CMAX + pos] = t;
            cand_e[b * CMAX + pos] = e;
            kept = true;
        }
    }
    red[t] = kept ? 0.0f : e;           // excluded mass (incl. overflow)
    __syncthreads();
    for (int off = 512; off > 0; off >>= 1) {
        if (t < off) red[t] += red[t + off];
        __syncthreads();
    }
    if (t == 0) { Carr[b] = min(cnt, CMAX); exclArr[b] = red[0]; }
}

// ---------------- Kernel C: out[b,q,:] = sum_k p * value[b,k,:] ----------
// 256 blocks x 1024 thr: block = 64 q-rows of one batch; wave = 4 rows.
// Candidate mask bits gathered once per row into SGPR u64s via ballot;
// inner loop is fixed-trip with linear LDS addresses (pipelines fully).
__global__ __launch_bounds__(1024)
void attn_kernel(const float* __restrict__ value, const int* __restrict__ mask,
                 const float* __restrict__ e_full,
                 const int* __restrict__ cand_k, const float* __restrict__ cand_e,
                 const int* __restrict__ Carr, const float* __restrict__ exclArr,
                 float* __restrict__ out) {
    __shared__ float4 ldsV4[NSTAGE * 64];   // 56 KB: candidate V rows
    __shared__ float  e_l[CMAX];
    __shared__ int    k_l[CMAX];

    const int wid   = threadIdx.x >> 6;
    const int lane  = threadIdx.x & 63;
    const int b     = blockIdx.x >> 4;      // 16 blocks per batch
    const int qtile = blockIdx.x & 15;      // 64 rows per block
    const int C     = Carr[b];
    const float excl = exclArr[b];

    if (threadIdx.x < CMAX) {
        e_l[threadIdx.x] = cand_e[b * CMAX + threadIdx.x];
        k_l[threadIdx.x] = cand_k[b * CMAX + threadIdx.x];
    }
    __syncthreads();

    const float4* vbase = (const float4*)(value + (size_t)b * NL * ND);
    const int nst = min(C, NSTAGE);
    for (int r = wid; r < nst; r += 16)
        ldsV4[r * 64 + lane] = vbase[(size_t)k_l[r] * 64 + lane];

    const int q0   = qtile * 64 + wid * 4;      // four consecutive q-rows
    const int row0 = b * NL + q0;
    const int* mrow0 = mask + (size_t)row0 * NL;

    // --- candidate-mask bits: u[c][r] bit j = mask[row r][cand (c*64+j)] ---
    const int nch = (C + 63) >> 6;              // 1 or 2
    unsigned long long u[2][4];
    float e_lane[2];
    #pragma unroll
    for (int c = 0; c < 2; ++c) {
        e_lane[c] = 0.0f;
        #pragma unroll
        for (int r = 0; r < 4; ++r) u[c][r] = 0ull;
        if (c < nch) {
            const int kj = k_l[c * 64 + lane];  // pad lanes: kj=0, e=0 -> inert
            e_lane[c] = e_l[c * 64 + lane];
            #pragma unroll
            for (int r = 0; r < 4; ++r) {
                int mv = mrow0[(size_t)r * NL + kj];
                u[c][r] = __ballot(mv != 0);
            }
        }
    }
    __syncthreads();   // ldsV4 staged

    // --- main loop: fixed trips, linear addresses, 4 rows amortize each V ---
    float4 acc[4];
    #pragma unroll
    for (int r = 0; r < 4; ++r) acc[r] = make_float4(0.f, 0.f, 0.f, 0.f);

    #pragma unroll
    for (int c = 0; c < 2; ++c) {
        if (c >= nch) break;                    // uniform
        #pragma unroll 16
        for (int j = 0; j < 64; ++j) {
            const int idx = c * 64 + j;
            const float ej = e_l[idx];
            float4 v;
            if (idx < NSTAGE) v = ldsV4[idx * 64 + lane];
            else              v = vbase[(size_t)k_l[idx] * 64 + lane];
            #pragma unroll
            for (int r = 0; r < 4; ++r) {
                const float wgt = ((u[c][r] >> j) & 1ull) ? ej : 0.0f;
                acc[r].x += wgt * v.x; acc[r].y += wgt * v.y;
                acc[r].z += wgt * v.z; acc[r].w += wgt * v.w;
            }
        }
    }

    // --- Z per row: lane-masked e reduce ---
    float Zr[4];
    #pragma unroll
    for (int r = 0; r < 4; ++r) {
        float t = 0.0f;
        #pragma unroll
        for (int c = 0; c < 2; ++c)
            t += ((u[c][r] >> lane) & 1ull) ? e_lane[c] : 0.0f;
        #pragma unroll
        for (int off = 32; off > 0; off >>= 1)
            t += __shfl_xor(t, off, 64);
        Zr[r] = t;
    }

    // --- epilogue + (near-never) exact dense fallback ---
    #pragma unroll
    for (int r = 0; r < 4; ++r) {
        const float Z = Zr[r];
        const int row = row0 + r;
        float4* orow = (float4*)(out + (size_t)row * ND);
        if (Z > 0.0f && excl <= RELCHK * Z) {
            const float inv = 1.0f / Z;
            orow[lane] = make_float4(acc[r].x * inv, acc[r].y * inv,
                                     acc[r].z * inv, acc[r].w * inv);
        } else {
            const int* mrow = mrow0 + (size_t)r * NL;
            float Zf = 0.0f;
            float4 af = make_float4(0.f, 0.f, 0.f, 0.f);
            for (int cc = 0; cc < NL / 64; ++cc) {
                int mk = mrow[cc * 64 + lane];
                unsigned long long bits = __ballot(mk != 0);
                while (bits) {
                    const int j = __builtin_ctzll(bits);
                    bits &= bits - 1;
                    const int k = cc * 64 + j;
                    const float e = e_full[b * NL + k];
                    float4 v = vbase[(size_t)k * 64 + lane];
                    Zf += e;
                    af.x += e * v.x; af.y += e * v.y;
                    af.z += e * v.z; af.w += e * v.w;
                }
            }
            if (Zf > 0.0f) {
                const float inv = 1.0f / Zf;
                orow[lane] = make_float4(af.x * inv, af.y * inv,
                                         af.z * inv, af.w * inv);
            } else {
                // all 1024 masked: softmax of constant -1e9 -> uniform average
                float4 s = make_float4(0.f, 0.f, 0.f, 0.f);
                for (int k = 0; k < NL; ++k) {
                    float4 v = vbase[(size_t)k * 64 + lane];
                    s.x += v.x; s.y += v.y; s.z += v.z; s.w += v.w;
                }
                const float inv = 1.0f / (float)NL;
                orow[lane] = make_float4(s.x * inv, s.y * inv,
                                         s.z * inv, s.w * inv);
            }
        }
    }
}

extern "C" void kernel_launch(void* const* d_in, const int* in_sizes, int n_in,
                              void* d_out, int out_size, void* d_ws, size_t ws_size,
                              hipStream_t stream) {
    // setup_inputs order: query, key, value, w, mask   (query unused!)
    const float* key   = (const float*)d_in[1];
    const float* value = (const float*)d_in[2];
    const float* w     = (const float*)d_in[3];
    const int*   mask  = (const int*)d_in[4];
    float*       outp  = (float*)d_out;

    float* ks     = (float*)d_ws;                    // 16*1024 f32
    float* e_full = ks + NB * NL;                    // 16*1024 f32
    int*   cand_k = (int*)(e_full + NB * NL);        // 16*128 i32
    float* cand_e = (float*)(cand_k + NB * CMAX);    // 16*128 f32
    int*   Carr   = (int*)(cand_e + NB * CMAX);      // 16 i32
    float* exclA  = (float*)(Carr + NB);             // 16 f32

    ks_kernel     <<<NB * NL / 4, 256, 0, stream>>>(key, w, ks);
    compact_kernel<<<NB, 1024, 0, stream>>>(ks, e_full, cand_k, cand_e, Carr, exclA);
    attn_kernel   <<<NB * NL / 64, 1024, 0, stream>>>(value, mask, e_full,
                                                      cand_k, cand_e, Carr, exclA, outp);
}

// Round 5
// 374.438 us; speedup vs baseline: 1.0336x; 1.0336x over previous
//
#include <hip/hip_runtime.h>
#include <math.h>

// Problem: B=16, LQ=1024, LK=1024, DK=256, DV=256, fp32 in/out, mask int32.
// Identity: softmax_k(q_s + k_s, mask) == mask-weighted softmax of k_s alone
// (q_s constant over k cancels; masked entries exactly -1e9 -> weight 0).
// query is never read. k_s ~ N(0,16^2): keep candidates e >= 1e-11*e_max
// (C ~ 30-90 per batch, E[C]~50), track exact excluded mass; per row verify
// excl <= 1e-4*Z else exact dense fallback (P ~ 2^-35 per row).
//
// R3 lesson: no dependent-address serial walks — fixed trips, linear LDS.
// R4 lesson: 1024-thr block defaulted to 64-VGPR cap -> scratch spills
// (WRITE_SIZE +10MB). Fix: __launch_bounds__(1024,4) => 128 VGPR cap,
// unroll 8 (not 16), NSTAGE=64 so chunk 0 is branch-free LDS.

#define NB     16
#define NL     1024
#define ND     256
#define CMAX   128      // candidate capacity (E[C]~50; overflow -> excl)
#define NSTAGE 64       // candidate V rows staged in LDS (64 KB)
#define THRESH 1e-11f
#define RELCHK 1e-4f

// ---------------- Kernel A: ks[b,k] = dot(key[b,k,:], w) -----------------
__global__ __launch_bounds__(256)
void ks_kernel(const float* __restrict__ key, const float* __restrict__ w,
               float* __restrict__ ks) {
    int wid  = threadIdx.x >> 6;
    int lane = threadIdx.x & 63;
    int row  = blockIdx.x * 4 + wid;               // 0 .. NB*NL-1
    const float4* krow = (const float4*)(key + (size_t)row * ND);
    float4 kv = krow[lane];
    float4 wv = ((const float4*)w)[lane];
    float p = kv.x * wv.x + kv.y * wv.y + kv.z * wv.z + kv.w * wv.w;
    #pragma unroll
    for (int off = 32; off > 0; off >>= 1)
        p += __shfl_xor(p, off, 64);
    if (lane == 0) ks[row] = p;
}

// ---- Kernel B: per batch: max, e=exp(ks-m), threshold compaction --------
// Candidate arrays zero-padded to CMAX (pad: k=0, e=0 -> inert).
__global__ __launch_bounds__(1024)
void compact_kernel(const float* __restrict__ ks, float* __restrict__ e_full,
                    int* __restrict__ cand_k, float* __restrict__ cand_e,
                    int* __restrict__ Carr, float* __restrict__ exclArr) {
    __shared__ float red[NL];
    __shared__ int cnt;
    const int b = blockIdx.x;
    const int t = threadIdx.x;

    float v = ks[b * NL + t];
    red[t] = v;
    if (t < CMAX) { cand_k[b * CMAX + t] = 0; cand_e[b * CMAX + t] = 0.0f; }
    if (t == 0) cnt = 0;
    __syncthreads();
    for (int off = 512; off > 0; off >>= 1) {
        if (t < off) red[t] = fmaxf(red[t], red[t + off]);
        __syncthreads();
    }
    float m = red[0];
    __syncthreads();

    float e = __expf(v - m);            // e in (0,1]
    e_full[b * NL + t] = e;
    bool kept = false;
    if (e >= THRESH) {
        int pos = atomicAdd(&cnt, 1);   // order irrelevant: any-order sum
        if (pos < CMAX) {
            cand_k[b * CMAX + pos] = t;
            cand_e[b * CMAX + pos] = e;
            kept = true;
        }
    }
    red[t] = kept ? 0.0f : e;           // excluded mass (incl. overflow)
    __syncthreads();
    for (int off = 512; off > 0; off >>= 1) {
        if (t < off) red[t] += red[t + off];
        __syncthreads();
    }
    if (t == 0) { Carr[b] = min(cnt, CMAX); exclArr[b] = red[0]; }
}

// ---------------- Kernel C: out[b,q,:] = sum_k p * value[b,k,:] ----------
// 256 blocks x 1024 thr: block = 64 q-rows of one batch; wave = 4 rows.
// Candidate mask bits in SGPR u64s via ballot; chunk 0 (first 64 cands) is
// a branch-free fixed-trip loop over LDS-staged V with linear addresses.
__global__ __launch_bounds__(1024, 4)   // 1 block/CU -> 128 VGPR cap, no spill
void attn_kernel(const float* __restrict__ value, const int* __restrict__ mask,
                 const float* __restrict__ e_full,
                 const int* __restrict__ cand_k, const float* __restrict__ cand_e,
                 const int* __restrict__ Carr, const float* __restrict__ exclArr,
                 float* __restrict__ out) {
    __shared__ float4 ldsV4[NSTAGE * 64];   // 64 KB: candidate V rows
    __shared__ float  e_l[CMAX];
    __shared__ int    k_l[CMAX];

    const int wid   = threadIdx.x >> 6;
    const int lane  = threadIdx.x & 63;
    const int b     = blockIdx.x >> 4;      // 16 blocks per batch
    const int qtile = blockIdx.x & 15;      // 64 rows per block
    const int C     = Carr[b];
    const float excl = exclArr[b];

    if (threadIdx.x < CMAX) {
        e_l[threadIdx.x] = cand_e[b * CMAX + threadIdx.x];
        k_l[threadIdx.x] = cand_k[b * CMAX + threadIdx.x];
    }
    __syncthreads();

    const float4* vbase = (const float4*)(value + (size_t)b * NL * ND);
    // stage 64 candidate V rows (pads stage row 0 harmlessly)
    #pragma unroll
    for (int r = 0; r < 4; ++r)
        ldsV4[(wid + 16 * r) * 64 + lane] = vbase[(size_t)k_l[wid + 16 * r] * 64 + lane];

    const int q0   = qtile * 64 + wid * 4;      // four consecutive q-rows
    const int row0 = b * NL + q0;
    const int* mrow0 = mask + (size_t)row0 * NL;

    // candidate-mask bits: u[c][r] bit j = mask[row r][cand (c*64+j)]
    const int nch = (C + 63) >> 6;              // 1 or 2
    unsigned long long u0[4], u1[4];
    const int   kj0 = k_l[lane];
    const float el0 = e_l[lane];
    #pragma unroll
    for (int r = 0; r < 4; ++r)
        u0[r] = __ballot(mrow0[(size_t)r * NL + kj0] != 0);
    float el1 = 0.0f;
    #pragma unroll
    for (int r = 0; r < 4; ++r) u1[r] = 0ull;
    if (nch > 1) {
        const int kj1 = k_l[64 + lane];
        el1 = e_l[64 + lane];
        #pragma unroll
        for (int r = 0; r < 4; ++r)
            u1[r] = __ballot(mrow0[(size_t)r * NL + kj1] != 0);
    }
    __syncthreads();   // ldsV4 staged

    float4 acc[4];
    #pragma unroll
    for (int r = 0; r < 4; ++r) acc[r] = make_float4(0.f, 0.f, 0.f, 0.f);

    // chunk 0: branch-free, pure LDS, fixed 64 trips
    #pragma unroll 8
    for (int j = 0; j < 64; ++j) {
        const float ej = e_l[j];
        const float4 v = ldsV4[j * 64 + lane];
        #pragma unroll
        for (int r = 0; r < 4; ++r) {
            const float wgt = ((u0[r] >> j) & 1ull) ? ej : 0.0f;
            acc[r].x += wgt * v.x; acc[r].y += wgt * v.y;
            acc[r].z += wgt * v.z; acc[r].w += wgt * v.w;
        }
    }
    // chunk 1 (C>64, ~2% of batches): from L2, independent addresses
    if (nch > 1) {
        #pragma unroll 4
        for (int j = 0; j < 64; ++j) {
            const float ej = e_l[64 + j];
            const float4 v = vbase[(size_t)k_l[64 + j] * 64 + lane];
            #pragma unroll
            for (int r = 0; r < 4; ++r) {
                const float wgt = ((u1[r] >> j) & 1ull) ? ej : 0.0f;
                acc[r].x += wgt * v.x; acc[r].y += wgt * v.y;
                acc[r].z += wgt * v.z; acc[r].w += wgt * v.w;
            }
        }
    }

    // Z per row: lane-masked e reduce
    float Zr[4];
    #pragma unroll
    for (int r = 0; r < 4; ++r) {
        float t = (((u0[r] >> lane) & 1ull) ? el0 : 0.0f)
                + (((u1[r] >> lane) & 1ull) ? el1 : 0.0f);
        #pragma unroll
        for (int off = 32; off > 0; off >>= 1)
            t += __shfl_xor(t, off, 64);
        Zr[r] = t;
    }

    // epilogue + (near-never) exact dense fallback
    #pragma unroll
    for (int r = 0; r < 4; ++r) {
        const float Z = Zr[r];
        const int row = row0 + r;
        float4* orow = (float4*)(out + (size_t)row * ND);
        if (Z > 0.0f && excl <= RELCHK * Z) {
            const float inv = 1.0f / Z;
            orow[lane] = make_float4(acc[r].x * inv, acc[r].y * inv,
                                     acc[r].z * inv, acc[r].w * inv);
        } else {
            const int* mrow = mrow0 + (size_t)r * NL;
            float Zf = 0.0f;
            float4 af = make_float4(0.f, 0.f, 0.f, 0.f);
            for (int cc = 0; cc < NL / 64; ++cc) {
                int mk = mrow[cc * 64 + lane];
                unsigned long long bits = __ballot(mk != 0);
                while (bits) {
                    const int j = __builtin_ctzll(bits);
                    bits &= bits - 1;
                    const int k = cc * 64 + j;
                    const float e = e_full[b * NL + k];
                    float4 v = vbase[(size_t)k * 64 + lane];
                    Zf += e;
                    af.x += e * v.x; af.y += e * v.y;
                    af.z += e * v.z; af.w += e * v.w;
                }
            }
            if (Zf > 0.0f) {
                const float inv = 1.0f / Zf;
                orow[lane] = make_float4(af.x * inv, af.y * inv,
                                         af.z * inv, af.w * inv);
            } else {
                // all 1024 masked: softmax of constant -1e9 -> uniform avg
                float4 s = make_float4(0.f, 0.f, 0.f, 0.f);
                for (int k = 0; k < NL; ++k) {
                    float4 v = vbase[(size_t)k * 64 + lane];
                    s.x += v.x; s.y += v.y; s.z += v.z; s.w += v.w;
                }
                const float inv = 1.0f / (float)NL;
                orow[lane] = make_float4(s.x * inv, s.y * inv,
                                         s.z * inv, s.w * inv);
            }
        }
    }
}

extern "C" void kernel_launch(void* const* d_in, const int* in_sizes, int n_in,
                              void* d_out, int out_size, void* d_ws, size_t ws_size,
                              hipStream_t stream) {
    // setup_inputs order: query, key, value, w, mask   (query unused!)
    const float* key   = (const float*)d_in[1];
    const float* value = (const float*)d_in[2];
    const float* w     = (const float*)d_in[3];
    const int*   mask  = (const int*)d_in[4];
    float*       outp  = (float*)d_out;

    float* ks     = (float*)d_ws;                    // 16*1024 f32
    float* e_full = ks + NB * NL;                    // 16*1024 f32
    int*   cand_k = (int*)(e_full + NB * NL);        // 16*128 i32
    float* cand_e = (float*)(cand_k + NB * CMAX);    // 16*128 f32
    int*   Carr   = (int*)(cand_e + NB * CMAX);      // 16 i32
    float* exclA  = (float*)(Carr + NB);             // 16 f32

    ks_kernel     <<<NB * NL / 4, 256, 0, stream>>>(key, w, ks);
    compact_kernel<<<NB, 1024, 0, stream>>>(ks, e_full, cand_k, cand_e, Carr, exclA);
    attn_kernel   <<<NB * NL / 64, 1024, 0, stream>>>(value, mask, e_full,
                                                      cand_k, cand_e, Carr, exclA, outp);
}

// Round 6
// 371.716 us; speedup vs baseline: 1.0412x; 1.0073x over previous
//
#include <hip/hip_runtime.h>
#include <math.h>

// Problem: B=16, LQ=1024, LK=1024, DK=256, DV=256, fp32 in/out, mask int32.
// Identity: softmax_k(q_s + k_s, mask) == mask-weighted softmax of k_s alone
// (q_s constant over k cancels; masked entries exactly -1e9 -> weight 0).
// query is never read. k_s ~ N(0,16^2): keep candidates e >= 1e-11*e_max
// (C ~ 30-90 per batch), track exact excluded mass; per row verify
// excl <= 1e-4*Z else exact dense fallback (P ~ 2^-35 per row).
//
// R3 lesson: no dependent-address serial walks — fixed trips, linear LDS.
// R4 lesson: 1024-thr block w/o launch_bounds -> 64-VGPR cap -> spills.
// R5 lesson: per-lane scattered mask gathers to cold HBM are latency-bound
// (~160 GB/s effective; R3/R4/R5 all ~250-270us). Mask must be read as a
// coalesced stream (R2 measured 742 GB/s): read full row with int4 loads,
// pack bits in registers, extract candidate bits via __shfl + __ballot.

#define NB     16
#define NL     1024
#define ND     256
#define CMAX   128      // candidate capacity (E[C]~50; overflow -> excl)
#define NSTAGE 64       // candidate V rows staged in LDS (64 KB)
#define THRESH 1e-11f
#define RELCHK 1e-4f

// ---------------- Kernel A: ks[b,k] = dot(key[b,k,:], w) -----------------
__global__ __launch_bounds__(256)
void ks_kernel(const float* __restrict__ key, const float* __restrict__ w,
               float* __restrict__ ks) {
    int wid  = threadIdx.x >> 6;
    int lane = threadIdx.x & 63;
    int row  = blockIdx.x * 4 + wid;               // 0 .. NB*NL-1
    const float4* krow = (const float4*)(key + (size_t)row * ND);
    float4 kv = krow[lane];
    float4 wv = ((const float4*)w)[lane];
    float p = kv.x * wv.x + kv.y * wv.y + kv.z * wv.z + kv.w * wv.w;
    #pragma unroll
    for (int off = 32; off > 0; off >>= 1)
        p += __shfl_xor(p, off, 64);
    if (lane == 0) ks[row] = p;
}

// ---- Kernel B: per batch: max, e=exp(ks-m), threshold compaction --------
// Candidate arrays zero-padded to CMAX (pad: k=0, e=0 -> inert).
__global__ __launch_bounds__(1024)
void compact_kernel(const float* __restrict__ ks, float* __restrict__ e_full,
                    int* __restrict__ cand_k, float* __restrict__ cand_e,
                    int* __restrict__ Carr, float* __restrict__ exclArr) {
    __shared__ float red[NL];
    __shared__ int cnt;
    const int b = blockIdx.x;
    const int t = threadIdx.x;

    float v = ks[b * NL + t];
    red[t] = v;
    if (t < CMAX) { cand_k[b * CMAX + t] = 0; cand_e[b * CMAX + t] = 0.0f; }
    if (t == 0) cnt = 0;
    __syncthreads();
    for (int off = 512; off > 0; off >>= 1) {
        if (t < off) red[t] = fmaxf(red[t], red[t + off]);
        __syncthreads();
    }
    float m = red[0];
    __syncthreads();

    float e = __expf(v - m);            // e in (0,1]
    e_full[b * NL + t] = e;
    bool kept = false;
    if (e >= THRESH) {
        int pos = atomicAdd(&cnt, 1);   // order irrelevant: any-order sum
        if (pos < CMAX) {
            cand_k[b * CMAX + pos] = t;
            cand_e[b * CMAX + pos] = e;
            kept = true;
        }
    }
    red[t] = kept ? 0.0f : e;           // excluded mass (incl. overflow)
    __syncthreads();
    for (int off = 512; off > 0; off >>= 1) {
        if (t < off) red[t] += red[t + off];
        __syncthreads();
    }
    if (t == 0) { Carr[b] = min(cnt, CMAX); exclArr[b] = red[0]; }
}

// ---------------- Kernel C: out[b,q,:] = sum_k p * value[b,k,:] ----------
// 256 blocks x 1024 thr: block = 64 q-rows of one batch; wave = 4 rows.
// Mask rows read COALESCED (4x int4 = 1 KB slabs), bits packed per lane,
// candidate bits extracted via shfl+ballot into SGPR u64s. Inner loop:
// branch-free fixed 64 trips over LDS-staged V with linear addresses.
__global__ __launch_bounds__(1024, 4)   // 128-VGPR cap, no spill (R4 lesson)
void attn_kernel(const float* __restrict__ value, const int* __restrict__ mask,
                 const float* __restrict__ e_full,
                 const int* __restrict__ cand_k, const float* __restrict__ cand_e,
                 const int* __restrict__ Carr, const float* __restrict__ exclArr,
                 float* __restrict__ out) {
    __shared__ float4 ldsV4[NSTAGE * 64];   // 64 KB: candidate V rows
    __shared__ float  e_l[CMAX];
    __shared__ int    k_l[CMAX];

    const int wid   = threadIdx.x >> 6;
    const int lane  = threadIdx.x & 63;
    const int b     = blockIdx.x >> 4;      // 16 blocks per batch
    const int qtile = blockIdx.x & 15;      // 64 rows per block
    const int C     = Carr[b];
    const float excl = exclArr[b];

    if (threadIdx.x < CMAX) {
        e_l[threadIdx.x] = cand_e[b * CMAX + threadIdx.x];
        k_l[threadIdx.x] = cand_k[b * CMAX + threadIdx.x];
    }
    __syncthreads();

    const float4* vbase = (const float4*)(value + (size_t)b * NL * ND);
    // stage 64 candidate V rows (pads stage row 0 harmlessly)
    #pragma unroll
    for (int r = 0; r < 4; ++r)
        ldsV4[(wid + 16 * r) * 64 + lane] = vbase[(size_t)k_l[wid + 16 * r] * 64 + lane];

    const int q0   = qtile * 64 + wid * 4;      // four consecutive q-rows
    const int row0 = b * NL + q0;
    const int* mrow0 = mask + (size_t)row0 * NL;

    // --- coalesced mask-row read + register bit-pack -------------------
    // Load i reads a contiguous 1 KB slab: lane holds ints i*256+lane*4+{0..3}
    // packed at bit i*4+c. Global int j lives in lane (j>>2)&63, bit (j>>8)*4+(j&3).
    unsigned int rb[4];
    #pragma unroll
    for (int r = 0; r < 4; ++r) {
        const int4* mrow4 = (const int4*)(mrow0 + (size_t)r * NL);
        unsigned int bits = 0;
        #pragma unroll
        for (int i = 0; i < 4; ++i) {
            int4 m = mrow4[i * 64 + lane];
            bits |= (m.x != 0 ? 1u : 0u) << (i * 4 + 0);
            bits |= (m.y != 0 ? 1u : 0u) << (i * 4 + 1);
            bits |= (m.z != 0 ? 1u : 0u) << (i * 4 + 2);
            bits |= (m.w != 0 ? 1u : 0u) << (i * 4 + 3);
        }
        rb[r] = bits;
    }

    // --- candidate-mask bits via shfl + ballot -> SGPR u64s ------------
    const int nch = (C + 63) >> 6;              // 1 or 2
    const int   kj0 = k_l[lane];
    const float el0 = e_l[lane];
    int   kj1 = 0;  float el1 = 0.0f;
    if (nch > 1) { kj1 = k_l[64 + lane]; el1 = e_l[64 + lane]; }

    unsigned long long u0[4], u1[4];
    #pragma unroll
    for (int r = 0; r < 4; ++r) {
        unsigned int w0 = __shfl(rb[r], (kj0 >> 2) & 63, 64);
        u0[r] = __ballot(((w0 >> (((kj0 >> 8) << 2) + (kj0 & 3))) & 1u) != 0);
        unsigned int w1 = __shfl(rb[r], (kj1 >> 2) & 63, 64);
        unsigned long long b1 =
            __ballot(((w1 >> (((kj1 >> 8) << 2) + (kj1 & 3))) & 1u) != 0);
        u1[r] = (nch > 1) ? b1 : 0ull;
    }
    __syncthreads();   // ldsV4 staged

    float4 acc[4];
    #pragma unroll
    for (int r = 0; r < 4; ++r) acc[r] = make_float4(0.f, 0.f, 0.f, 0.f);

    // chunk 0: branch-free, pure LDS, fixed 64 trips
    #pragma unroll 8
    for (int j = 0; j < 64; ++j) {
        const float ej = e_l[j];
        const float4 v = ldsV4[j * 64 + lane];
        #pragma unroll
        for (int r = 0; r < 4; ++r) {
            const float wgt = ((u0[r] >> j) & 1ull) ? ej : 0.0f;
            acc[r].x += wgt * v.x; acc[r].y += wgt * v.y;
            acc[r].z += wgt * v.z; acc[r].w += wgt * v.w;
        }
    }
    // chunk 1 (C>64, ~2% of batches): from L2, independent addresses
    if (nch > 1) {
        #pragma unroll 4
        for (int j = 0; j < 64; ++j) {
            const float ej = e_l[64 + j];
            const float4 v = vbase[(size_t)k_l[64 + j] * 64 + lane];
            #pragma unroll
            for (int r = 0; r < 4; ++r) {
                const float wgt = ((u1[r] >> j) & 1ull) ? ej : 0.0f;
                acc[r].x += wgt * v.x; acc[r].y += wgt * v.y;
                acc[r].z += wgt * v.z; acc[r].w += wgt * v.w;
            }
        }
    }

    // Z per row: lane-masked e reduce
    float Zr[4];
    #pragma unroll
    for (int r = 0; r < 4; ++r) {
        float t = (((u0[r] >> lane) & 1ull) ? el0 : 0.0f)
                + (((u1[r] >> lane) & 1ull) ? el1 : 0.0f);
        #pragma unroll
        for (int off = 32; off > 0; off >>= 1)
            t += __shfl_xor(t, off, 64);
        Zr[r] = t;
    }

    // epilogue + (near-never) exact dense fallback
    #pragma unroll
    for (int r = 0; r < 4; ++r) {
        const float Z = Zr[r];
        const int row = row0 + r;
        float4* orow = (float4*)(out + (size_t)row * ND);
        if (Z > 0.0f && excl <= RELCHK * Z) {
            const float inv = 1.0f / Z;
            orow[lane] = make_float4(acc[r].x * inv, acc[r].y * inv,
                                     acc[r].z * inv, acc[r].w * inv);
        } else {
            const int* mrow = mrow0 + (size_t)r * NL;
            float Zf = 0.0f;
            float4 af = make_float4(0.f, 0.f, 0.f, 0.f);
            for (int cc = 0; cc < NL / 64; ++cc) {
                int mk = mrow[cc * 64 + lane];
                unsigned long long bits = __ballot(mk != 0);
                while (bits) {
                    const int j = __builtin_ctzll(bits);
                    bits &= bits - 1;
                    const int k = cc * 64 + j;
                    const float e = e_full[b * NL + k];
                    float4 v = vbase[(size_t)k * 64 + lane];
                    Zf += e;
                    af.x += e * v.x; af.y += e * v.y;
                    af.z += e * v.z; af.w += e * v.w;
                }
            }
            if (Zf > 0.0f) {
                const float inv = 1.0f / Zf;
                orow[lane] = make_float4(af.x * inv, af.y * inv,
                                         af.z * inv, af.w * inv);
            } else {
                // all 1024 masked: softmax of constant -1e9 -> uniform avg
                float4 s = make_float4(0.f, 0.f, 0.f, 0.f);
                for (int k = 0; k < NL; ++k) {
                    float4 v = vbase[(size_t)k * 64 + lane];
                    s.x += v.x; s.y += v.y; s.z += v.z; s.w += v.w;
                }
                const float inv = 1.0f / (float)NL;
                orow[lane] = make_float4(s.x * inv, s.y * inv,
                                         s.z * inv, s.w * inv);
            }
        }
    }
}

extern "C" void kernel_launch(void* const* d_in, const int* in_sizes, int n_in,
                              void* d_out, int out_size, void* d_ws, size_t ws_size,
                              hipStream_t stream) {
    // setup_inputs order: query, key, value, w, mask   (query unused!)
    const float* key   = (const float*)d_in[1];
    const float* value = (const float*)d_in[2];
    const float* w     = (const float*)d_in[3];
    const int*   mask  = (const int*)d_in[4];
    float*       outp  = (float*)d_out;

    float* ks     = (float*)d_ws;                    // 16*1024 f32
    float* e_full = ks + NB * NL;                    // 16*1024 f32
    int*   cand_k = (int*)(e_full + NB * NL);        // 16*128 i32
    float* cand_e = (float*)(cand_k + NB * CMAX);    // 16*128 f32
    int*   Carr   = (int*)(cand_e + NB * CMAX);      // 16 i32
    float* exclA  = (float*)(Carr + NB);             // 16 f32

    ks_kernel     <<<NB * NL / 4, 256, 0, stream>>>(key, w, ks);
    compact_kernel<<<NB, 1024, 0, stream>>>(ks, e_full, cand_k, cand_e, Carr, exclA);
    attn_kernel   <<<NB * NL / 64, 1024, 0, stream>>>(value, mask, e_full,
                                                      cand_k, cand_e, Carr, exclA, outp);
}